// Round 10
// baseline (152.574 us; speedup 1.0000x reference)
//
#include <hip/hip_runtime.h>
#include <hip/hip_fp16.h>
#include <math.h>

#define N_NODES 10000
#define N_EDGES 160000
#define B_ 8
#define D_ 64
#define BD 512          // B_*D_
#define ROWS 80000      // N_NODES*B_
#define SLICE 640000    // N_NODES*64 words per batch-slice
#define CAP 48          // max edges kept per node; P(Poisson(16) >= 48) ~ 6e-11
#define CAPR 56         // bucket row stride

typedef _Float16 f16x8 __attribute__((ext_vector_type(8)));
typedef float f32x4 __attribute__((ext_vector_type(4)));
typedef float f4v __attribute__((ext_vector_type(4)));
typedef unsigned int u32;

union HU { _Float16 f; unsigned short u; };
union HC { u32 u; __half2 h; };

// ---------------- fused prep: bucket-scatter (blocks 0..624) + MFMA proj (625..1874) ----
// scatter: bucket[d*CAPR + pos] = src | (half(dist*log2e) << 16). Pad slots stay 0
//          (memset) -> decode {src=0, hd=0} -> exp contribution exactly 1.
// proj: P[m][c] = sum_k state[m][k]*W[(c>=64?64:0)+k][c&63], slice-major planar-quad:
//   row m = node*8+b -> G words [b*SLICE + node*64 + q*4 .. +3] = {p01,p23,x01,x23}
//                        Pd[b*SLICE + node*64 + d] = half(p_dst)   (d-linear)
// B-fragments are loaded DIRECTLY from weight (32 KB, L1/L2-resident, identical for
// every block) -- no LDS transpose stage.
__global__ void __launch_bounds__(256) prep_kernel(
    const int* __restrict__ src, const int* __restrict__ dst,
    const float* __restrict__ dist, int* __restrict__ counts, u32* __restrict__ bucket,
    const float* __restrict__ state, const float* __restrict__ weight,
    u32* __restrict__ G, __half* __restrict__ Pd) {
    __shared__ _Float16 At[64 * 72];          // 9 KB   (fp16 state tile, also x source)
    __shared__ unsigned short Ps2[64 * 68];   // 8.7 KB (p_src halves, d-linear)
    __shared__ unsigned short Ps[64 * 64];    // 8 KB   (p_dst halves, d-linear)
    int bid = blockIdx.x;
    int tid = threadIdx.x;

    if (bid < 625) {
        // ---- scatter (625*256 == N_EDGES exactly) ----
        int e = bid * 256 + tid;
        int s = src[e];
        int d = dst[e];
        float di = dist[e];
        int pos = atomicAdd(&counts[d], 1);
        if (pos < CAP) {
            unsigned short hd = __half_as_ushort(__float2half_rn(di * 1.44269504f));
            bucket[d * CAPR + pos] = (u32)s | ((u32)hd << 16);
        }
        return;
    }

    // ---- proj ----
    int row0 = (bid - 625) * 64;
    int wave = tid >> 6, lane = tid & 63;
    int quad = lane >> 4, m16 = lane & 15;
    int m_loc = wave * 16 + m16;

    // stage state tile (read-once stream) -> fp16 LDS
    const f4v* st4 = (const f4v*)(state + (size_t)row0 * 64);
    for (int i = tid; i < 1024; i += 256) {
        int r = i >> 4, c4 = (i & 15) << 2;
        f4v v = __builtin_nontemporal_load(&st4[i]);
        union { short4 s; _Float16 h[4]; } u;
        u.h[0] = (_Float16)v[0]; u.h[1] = (_Float16)v[1];
        u.h[2] = (_Float16)v[2]; u.h[3] = (_Float16)v[3];
        *(short4*)&At[r * 72 + c4] = u.s;
    }

    // B-fragments straight from global weight: B[k][n] = W[(h*64+k)*64 + (n&63)],
    // lane (quad, m16): b0 k=quad*8+j, b1 k=32+quad*8+j, n = tcol*16+m16.
    f16x8 bf0[8], bf1[8];
#pragma unroll
    for (int tcol = 0; tcol < 8; tcol++) {
        const float* wp = weight + ((tcol >= 4) ? 4096 : 0) + ((tcol * 16 + m16) & 63);
#pragma unroll
        for (int j = 0; j < 8; j++) {
            bf0[tcol][j] = (_Float16)wp[(quad * 8 + j) * 64];
            bf1[tcol][j] = (_Float16)wp[(32 + quad * 8 + j) * 64];
        }
    }
    __syncthreads();

    f16x8 a0 = *(const f16x8*)&At[m_loc * 72 + quad * 8];
    f16x8 a1 = *(const f16x8*)&At[m_loc * 72 + 32 + quad * 8];

#pragma unroll
    for (int tcol = 0; tcol < 8; tcol++) {
        int n = tcol * 16 + m16;
        f32x4 acc = {0.f, 0.f, 0.f, 0.f};
        acc = __builtin_amdgcn_mfma_f32_16x16x32_f16(a0, bf0[tcol], acc, 0, 0, 0);
        acc = __builtin_amdgcn_mfma_f32_16x16x32_f16(a1, bf1[tcol], acc, 0, 0, 0);
#pragma unroll
        for (int r = 0; r < 4; r++) {
            int ml = wave * 16 + quad * 4 + r;
            unsigned short ph = __half_as_ushort(__float2half_rn(acc[r]));
            if (tcol < 4) Ps2[ml * 68 + n] = ph;
            else          Ps[ml * 64 + (n - 64)] = ph;
        }
    }
    __syncthreads();

    // coalesced G write, planar-quad: one float4 per (row, quad) = {p01,p23,x01,x23}
    const u32* Ps2w = (const u32*)Ps2;
    const u32* Atw = (const u32*)At;
    for (int i = tid; i < 1024; i += 256) {
        int row = i >> 4, q = i & 15;
        int m = row0 + row;
        size_t base = (size_t)(m & 7) * SLICE + (size_t)(m >> 3) * 64;
        u32 p01 = Ps2w[row * 34 + q * 2];
        u32 p23 = Ps2w[row * 34 + q * 2 + 1];
        u32 x01 = Atw[row * 36 + q * 2];
        u32 x23 = Atw[row * 36 + q * 2 + 1];
        float4 v = make_float4(__uint_as_float(p01), __uint_as_float(p23),
                               __uint_as_float(x01), __uint_as_float(x23));
        *(float4*)&G[base + q * 4] = v;
    }
    // coalesced Pd write: 512 float4 (8 lanes = one row's 128 B)
    for (int i = tid; i < 512; i += 256) {
        int row = i >> 3, seg = i & 7;
        int m = row0 + row;
        size_t base = (size_t)(m & 7) * SLICE + (size_t)(m >> 3) * 64;
        *(float4*)&Pd[base + seg * 8] = *(const float4*)&Ps[row * 64 + seg * 8];
    }
}

// ---------------- fused segment-softmax + aggregate: planar-quad, maskless, 4-edge pad --
// 4 waves/block; wave w -> node grp*4+w; slice b = blockIdx&7 (XCD-resident G slice).
// Edge count padded to a multiple of 4 (avg waste ~9% vs 22% at 8); pad records
// {src=0, hd=0} give ex=1 exactly, gathering node 0's slot; pollution subtracted
// exactly after the reduce. No clamps/masks in the loop; 1-deep prefetch.
__global__ void __launch_bounds__(256) gat_aggregate(
    const u32* __restrict__ G,          // planar-quad slice-major [b][node][16 quads][4 words]
    const __half* __restrict__ Pds,     // slice-major [b][node][64], d-linear
    const int* __restrict__ counts,
    const u32* __restrict__ bucket,
    float* __restrict__ out) {
    int bid = blockIdx.x;
    int b = bid & 7;
    int grp = bid >> 3;
    int wave = threadIdx.x >> 6;
    int lane = threadIdx.x & 63;
    int n = (grp << 2) + wave;
    int eidx = lane >> 4;    // edge group 0..3
    int lpart = lane & 15;   // element quad 0..15

    const u32* Gb = G + (size_t)b * SLICE;
    const __half* Pb = Pds + (size_t)b * SLICE;

    union { double d; __half2 h[2]; } pdu;
    pdu.d = *(const double*)(Pb + n * 64 + lpart * 4);
    __half2 pd01 = pdu.h[0], pd23 = pdu.h[1];

    int cnt = counts[n];
    if (cnt > CAP) cnt = CAP;
    int padded = (cnt + 3) & ~3;
    const u32* ep = bucket + n * CAPR;

    const __half2 c06 = __float2half2_rn(0.6f);
    const __half2 c04 = __float2half2_rn(0.4f);
    const u32 ABSM = 0x7fff7fffu;

    __half2 l01 = __float2half2_rn(0.f), l23 = l01;
    __half2 o01 = l01, o23 = l01;

    if (padded > 0) {
        u32 rec = ep[eidx];
        float4 g = *(const float4*)(Gb + (size_t)(rec & 0xffffu) * 64 + lpart * 4);
        __half hd = __ushort_as_half((unsigned short)(rec >> 16));
        __half2 dd = __halves2half2(hd, hd);

        int j = 0;
        for (;;) {
            int jn = j + 4;
            bool more = jn < padded;   // wave-uniform
            float4 g2; __half2 dd2;
            if (more) {
                u32 rec2 = ep[jn + eidx];
                g2 = *(const float4*)(Gb + (size_t)(rec2 & 0xffffu) * 64 + lpart * 4);
                __half h2 = __ushort_as_half((unsigned short)(rec2 >> 16));
                dd2 = __halves2half2(h2, h2);
            }
            union { float4 f; __half2 h[4]; } gu; gu.f = g;
            __half2 p01 = gu.h[0], p23 = gu.h[1];     // planar: no repack
            __half2 x01 = gu.h[2], x23 = gu.h[3];
            __half2 z01 = __hadd2(p01, pd01);
            __half2 z23 = __hadd2(p23, pd23);
            HC az01, az23, zz01, zz23;
            zz01.h = z01; zz23.h = z23;
            az01.u = zz01.u & ABSM;           // |z|
            az23.u = zz23.u & ABSM;
            __half2 lk01 = __hfma2(az01.h, c04, __hmul2(z01, c06));  // leaky_relu(0.2)
            __half2 lk23 = __hfma2(az23.h, c04, __hmul2(z23, c06));
            __half2 a01 = __hmul2(lk01, dd);
            __half2 a23 = __hmul2(lk23, dd);
            __half2 e01 = __halves2half2(hexp2(__low2half(a01)), hexp2(__high2half(a01)));
            __half2 e23 = __halves2half2(hexp2(__low2half(a23)), hexp2(__high2half(a23)));
            l01 = __hadd2(l01, e01);
            l23 = __hadd2(l23, e23);
            o01 = __hfma2(e01, x01, o01);
            o23 = __hfma2(e23, x23, o23);
            if (!more) break;
            j = jn; g = g2; dd = dd2;
        }
        // fold the 4 edge groups (lanes 16/32 apart)
#pragma unroll
        for (int m = 16; m <= 32; m <<= 1) {
            HC c;
            c.u = (u32)__shfl_xor((int)((HC){.h = l01}).u, m, 64); l01 = __hadd2(l01, c.h);
            c.u = (u32)__shfl_xor((int)((HC){.h = l23}).u, m, 64); l23 = __hadd2(l23, c.h);
            c.u = (u32)__shfl_xor((int)((HC){.h = o01}).u, m, 64); o01 = __hadd2(o01, c.h);
            c.u = (u32)__shfl_xor((int)((HC){.h = o23}).u, m, 64); o23 = __hadd2(o23, c.h);
        }
        // exact pad correction: each pad contributed ex=1 and x = node0's state
        int npads = padded - cnt;
        if (npads) {
            float4 g0 = *(const float4*)(Gb + lpart * 4);   // node 0 slot
            union { float4 f; __half2 h[4]; } g0u; g0u.f = g0;
            __half2 np = __float2half2_rn((float)npads);
            l01 = __hsub2(l01, np);
            l23 = __hsub2(l23, np);
            __half2 nneg = __hneg2(np);
            o01 = __hfma2(nneg, g0u.h[2], o01);
            o23 = __hfma2(nneg, g0u.h[3], o23);
        }
    }
    if (eidx == 0) {
        float4 r;
        if (cnt > 0) {
            float l0 = __low2float(l01), l1 = __high2float(l01);
            float l2 = __low2float(l23), l3 = __high2float(l23);
            float o0 = __low2float(o01), o1 = __high2float(o01);
            float o2 = __low2float(o23), o3 = __high2float(o23);
            r.x = fmaxf(o0 * __builtin_amdgcn_rcpf(l0), 0.f);
            r.y = fmaxf(o1 * __builtin_amdgcn_rcpf(l1), 0.f);
            r.z = fmaxf(o2 * __builtin_amdgcn_rcpf(l2), 0.f);
            r.w = fmaxf(o3 * __builtin_amdgcn_rcpf(l3), 0.f);
        } else {
            r = make_float4(0.f, 0.f, 0.f, 0.f);
        }
        *(float4*)(out + (size_t)n * BD + b * 64 + lpart * 4) = r;
    }
}

extern "C" void kernel_launch(void* const* d_in, const int* in_sizes, int n_in,
                              void* d_out, int out_size, void* d_ws, size_t ws_size,
                              hipStream_t stream) {
    const float* state  = (const float*)d_in[0];
    // d_in[1] = feature (unused by the math)
    const float* weight = (const float*)d_in[2];
    const int*   src    = (const int*)d_in[3];
    const int*   dst    = (const int*)d_in[4];
    const float* dist   = (const float*)d_in[5];

    // workspace layout (16B-aligned head first): total ~33 MB
    u32*    G      = (u32*)d_ws;                            // 8*SLICE u32 = 20.48 MB
    __half* Pd     = (__half*)(G + (size_t)8 * SLICE);      // 8*SLICE half = 10.24 MB
    u32*    bucket = (u32*)(Pd + (size_t)8 * SLICE);        // N*CAPR u32 = 2.24 MB
    int*    counts = (int*)(bucket + (size_t)N_NODES * CAPR); // N ints (contiguous after bucket)

    // one memset zeroes bucket (pad records decode as {src=0, hd=0}) and counts
    hipMemsetAsync(bucket, 0, ((size_t)N_NODES * CAPR + N_NODES) * sizeof(u32), stream);
    prep_kernel<<<1875, 256, 0, stream>>>(src, dst, dist, counts, bucket,
                                          state, weight, G, Pd);
    gat_aggregate<<<N_NODES * 2, 256, 0, stream>>>(G, Pd, counts, bucket, (float*)d_out);
}

// Round 11
// 142.184 us; speedup vs baseline: 1.0731x; 1.0731x over previous
//
#include <hip/hip_runtime.h>
#include <hip/hip_fp16.h>
#include <math.h>

#define N_NODES 10000
#define N_EDGES 160000
#define B_ 8
#define D_ 64
#define BD 512          // B_*D_
#define ROWS 80000      // N_NODES*B_
#define SLICE 640000    // N_NODES*64 words per batch-slice
#define CAP 48          // max edges kept per node; P(Poisson(16) >= 48) ~ 6e-11
#define CAPR 56         // bucket row stride

typedef _Float16 f16x8 __attribute__((ext_vector_type(8)));
typedef float f32x4 __attribute__((ext_vector_type(4)));
typedef float f4v __attribute__((ext_vector_type(4)));
typedef unsigned int u32;

union HU { _Float16 f; unsigned short u; };
union HC { u32 u; __half2 h; };

// ---------------- fused prep: bucket-scatter (blocks 0..624) + MFMA proj (625..1874) ----
// scatter: bucket[d*CAPR + pos] = src | (half(dist*log2e) << 16). Pad slots stay 0
//          (memset) -> decode {src=0, hd=0} -> exp contribution exactly 1.
// proj: P[m][c] = sum_k state[m][k]*W[(c>=64?64:0)+k][c&63], slice-major planar-quad:
//   row m = node*8+b -> G words [b*SLICE + node*64 + q*4 .. +3] = {p01,p23,x01,x23}
//                        Pd[b*SLICE + node*64 + d] = half(p_dst)   (d-linear)
// LDS: Bt (18.4 KB) is DEAD after B-fragments are hoisted to registers, so its space
// is reused for the Ps2/Ps output staging -> 27.6 KB total -> 5 blocks/CU (vs 3 at
// 44.5 KB), doubling latency-hiding for the load->mfma->store chain.
__global__ void __launch_bounds__(256, 4) prep_kernel(
    const int* __restrict__ src, const int* __restrict__ dst,
    const float* __restrict__ dist, int* __restrict__ counts, u32* __restrict__ bucket,
    const float* __restrict__ state, const float* __restrict__ weight,
    u32* __restrict__ G, __half* __restrict__ Pd) {
    __shared__ _Float16 At[64 * 72];          // 9 KB  (fp16 state tile, also x source)
    __shared__ char smemB[128 * 72 * 2];      // 18.4 KB: Bt, then Ps2+Ps
    _Float16* Bt = (_Float16*)smemB;                        // [128][72]
    unsigned short* Ps2 = (unsigned short*)smemB;           // [64][68] p_src
    unsigned short* Ps  = (unsigned short*)(smemB + 8704);  // [64][64] p_dst
    int bid = blockIdx.x;
    int tid = threadIdx.x;

    if (bid < 625) {
        // ---- scatter (625*256 == N_EDGES exactly) ----
        int e = bid * 256 + tid;
        int s = src[e];
        int d = dst[e];
        float di = dist[e];
        int pos = atomicAdd(&counts[d], 1);
        if (pos < CAP) {
            unsigned short hd = __half_as_ushort(__float2half_rn(di * 1.44269504f));
            bucket[d * CAPR + pos] = (u32)s | ((u32)hd << 16);
        }
        return;
    }

    // ---- proj ----
    int row0 = (bid - 625) * 64;
    int wave = tid >> 6, lane = tid & 63;
    int quad = lane >> 4, m16 = lane & 15;
    int m_loc = wave * 16 + m16;

    // stage state tile (read-once stream) -> fp16 LDS
    const f4v* st4 = (const f4v*)(state + (size_t)row0 * 64);
    for (int i = tid; i < 1024; i += 256) {
        int r = i >> 4, c4 = (i & 15) << 2;
        f4v v = __builtin_nontemporal_load(&st4[i]);
        union { short4 s; _Float16 h[4]; } u;
        u.h[0] = (_Float16)v[0]; u.h[1] = (_Float16)v[1];
        u.h[2] = (_Float16)v[2]; u.h[3] = (_Float16)v[3];
        *(short4*)&At[r * 72 + c4] = u.s;
    }
    // stage weight (32 KB, L2-resident across blocks) transposed -> Bt[n][k]
    const f4v* w4 = (const f4v*)weight;
    for (int i = tid; i < 2048; i += 256) {
        int r = i >> 4, c4 = (i & 15) << 2;    // r in [0,128): r = h*64+k
        f4v v = w4[i];
        int h = r >> 6, k = r & 63;
        int nb = h * 64 + c4;
        Bt[(nb + 0) * 72 + k] = (_Float16)v[0];
        Bt[(nb + 1) * 72 + k] = (_Float16)v[1];
        Bt[(nb + 2) * 72 + k] = (_Float16)v[2];
        Bt[(nb + 3) * 72 + k] = (_Float16)v[3];
    }
    __syncthreads();

    // hoist all B-fragments into registers; Bt LDS becomes dead after this
    f16x8 bf0[8], bf1[8];
#pragma unroll
    for (int tcol = 0; tcol < 8; tcol++) {
        int n = tcol * 16 + m16;
        bf0[tcol] = *(const f16x8*)&Bt[n * 72 + quad * 8];
        bf1[tcol] = *(const f16x8*)&Bt[n * 72 + 32 + quad * 8];
    }
    f16x8 a0 = *(const f16x8*)&At[m_loc * 72 + quad * 8];
    f16x8 a1 = *(const f16x8*)&At[m_loc * 72 + 32 + quad * 8];
    __syncthreads();   // everyone done with Bt; reuse as Ps2/Ps

#pragma unroll
    for (int tcol = 0; tcol < 8; tcol++) {
        int n = tcol * 16 + m16;
        f32x4 acc = {0.f, 0.f, 0.f, 0.f};
        acc = __builtin_amdgcn_mfma_f32_16x16x32_f16(a0, bf0[tcol], acc, 0, 0, 0);
        acc = __builtin_amdgcn_mfma_f32_16x16x32_f16(a1, bf1[tcol], acc, 0, 0, 0);
#pragma unroll
        for (int r = 0; r < 4; r++) {
            int ml = wave * 16 + quad * 4 + r;
            unsigned short ph = __half_as_ushort(__float2half_rn(acc[r]));
            if (tcol < 4) Ps2[ml * 68 + n] = ph;
            else          Ps[ml * 64 + (n - 64)] = ph;
        }
    }
    __syncthreads();

    // coalesced G write, planar-quad: one float4 per (row, quad) = {p01,p23,x01,x23}
    const u32* Ps2w = (const u32*)Ps2;
    const u32* Atw = (const u32*)At;
    for (int i = tid; i < 1024; i += 256) {
        int row = i >> 4, q = i & 15;
        int m = row0 + row;
        size_t base = (size_t)(m & 7) * SLICE + (size_t)(m >> 3) * 64;
        u32 p01 = Ps2w[row * 34 + q * 2];
        u32 p23 = Ps2w[row * 34 + q * 2 + 1];
        u32 x01 = Atw[row * 36 + q * 2];
        u32 x23 = Atw[row * 36 + q * 2 + 1];
        float4 v = make_float4(__uint_as_float(p01), __uint_as_float(p23),
                               __uint_as_float(x01), __uint_as_float(x23));
        *(float4*)&G[base + q * 4] = v;
    }
    // coalesced Pd write: 512 float4 (8 lanes = one row's 128 B)
    for (int i = tid; i < 512; i += 256) {
        int row = i >> 3, seg = i & 7;
        int m = row0 + row;
        size_t base = (size_t)(m & 7) * SLICE + (size_t)(m >> 3) * 64;
        *(float4*)&Pd[base + seg * 8] = *(const float4*)&Ps[row * 64 + seg * 8];
    }
}

// ---------------- fused segment-softmax + aggregate -----------------------------------
// planar-quad, maskless; pad to multiple of 4; 8-edge dual-chain main loop over
// full8 = padded4 & ~7, plus one 4-edge tail chain if a 4-remainder exists.
// Pads {src=0, hd=0} contribute ex=1 exactly (gather node 0's slot); corrected after
// the reduce. 4 waves/block; wave w -> node grp*4+w; slice b = blockIdx&7.
__global__ void __launch_bounds__(256) gat_aggregate(
    const u32* __restrict__ G,          // planar-quad slice-major [b][node][16 quads][4 words]
    const __half* __restrict__ Pds,     // slice-major [b][node][64], d-linear
    const int* __restrict__ counts,
    const u32* __restrict__ bucket,
    float* __restrict__ out) {
    int bid = blockIdx.x;
    int b = bid & 7;
    int grp = bid >> 3;
    int wave = threadIdx.x >> 6;
    int lane = threadIdx.x & 63;
    int n = (grp << 2) + wave;
    int eidx = lane >> 4;    // edge group 0..3
    int lpart = lane & 15;   // element quad 0..15

    const u32* Gb = G + (size_t)b * SLICE;
    const __half* Pb = Pds + (size_t)b * SLICE;

    union { double d; __half2 h[2]; } pdu;
    pdu.d = *(const double*)(Pb + n * 64 + lpart * 4);
    __half2 pd01 = pdu.h[0], pd23 = pdu.h[1];

    int cnt = counts[n];
    if (cnt > CAP) cnt = CAP;
    int padded4 = (cnt + 3) & ~3;
    int full8 = padded4 & ~7;
    const u32* ep = bucket + n * CAPR;

    const __half2 c06 = __float2half2_rn(0.6f);
    const __half2 c04 = __float2half2_rn(0.4f);
    const u32 ABSM = 0x7fff7fffu;

    __half2 l01 = __float2half2_rn(0.f), l23 = l01;
    __half2 o01 = l01, o23 = l01;

    auto body = [&](float4 g, __half2 dd) {
        union { float4 f; __half2 h[4]; } gu; gu.f = g;
        __half2 p01 = gu.h[0], p23 = gu.h[1];     // planar: no repack
        __half2 x01 = gu.h[2], x23 = gu.h[3];
        __half2 z01 = __hadd2(p01, pd01);
        __half2 z23 = __hadd2(p23, pd23);
        HC az01, az23, zz01, zz23;
        zz01.h = z01; zz23.h = z23;
        az01.u = zz01.u & ABSM;           // |z|
        az23.u = zz23.u & ABSM;
        __half2 lk01 = __hfma2(az01.h, c04, __hmul2(z01, c06));  // leaky_relu(0.2)
        __half2 lk23 = __hfma2(az23.h, c04, __hmul2(z23, c06));
        __half2 a01 = __hmul2(lk01, dd);
        __half2 a23 = __hmul2(lk23, dd);
        __half2 e01 = __halves2half2(hexp2(__low2half(a01)), hexp2(__high2half(a01)));
        __half2 e23 = __halves2half2(hexp2(__low2half(a23)), hexp2(__high2half(a23)));
        l01 = __hadd2(l01, e01);
        l23 = __hadd2(l23, e23);
        o01 = __hfma2(e01, x01, o01);
        o23 = __hfma2(e23, x23, o23);
    };

    if (full8 > 0) {
        u32 recA = ep[eidx];
        u32 recB = ep[4 + eidx];
        float4 gA = *(const float4*)(Gb + (size_t)(recA & 0xffffu) * 64 + lpart * 4);
        float4 gB = *(const float4*)(Gb + (size_t)(recB & 0xffffu) * 64 + lpart * 4);
        __half hA = __ushort_as_half((unsigned short)(recA >> 16));
        __half hB = __ushort_as_half((unsigned short)(recB >> 16));
        __half2 dA = __halves2half2(hA, hA);
        __half2 dB = __halves2half2(hB, hB);

        int j = 0;
        for (;;) {
            int jn = j + 8;
            bool more = jn < full8;   // wave-uniform
            float4 gA2, gB2; __half2 dA2, dB2;
            if (more) {
                u32 rA2 = ep[jn + eidx];
                u32 rB2 = ep[jn + 4 + eidx];
                gA2 = *(const float4*)(Gb + (size_t)(rA2 & 0xffffu) * 64 + lpart * 4);
                gB2 = *(const float4*)(Gb + (size_t)(rB2 & 0xffffu) * 64 + lpart * 4);
                __half h2a = __ushort_as_half((unsigned short)(rA2 >> 16));
                __half h2b = __ushort_as_half((unsigned short)(rB2 >> 16));
                dA2 = __halves2half2(h2a, h2a);
                dB2 = __halves2half2(h2b, h2b);
            }
            body(gA, dA);
            body(gB, dB);
            if (!more) break;
            j = jn; gA = gA2; gB = gB2; dA = dA2; dB = dB2;
        }
    }
    if (padded4 > full8) {
        // one 4-edge tail chain (indices full8..full8+3 < padded4, pads zeroed)
        u32 rec = ep[full8 + eidx];
        float4 g = *(const float4*)(Gb + (size_t)(rec & 0xffffu) * 64 + lpart * 4);
        __half hd = __ushort_as_half((unsigned short)(rec >> 16));
        body(g, __halves2half2(hd, hd));
    }

    if (cnt > 0) {
        // fold the 4 edge groups (lanes 16/32 apart)
#pragma unroll
        for (int m = 16; m <= 32; m <<= 1) {
            HC c;
            c.u = (u32)__shfl_xor((int)((HC){.h = l01}).u, m, 64); l01 = __hadd2(l01, c.h);
            c.u = (u32)__shfl_xor((int)((HC){.h = l23}).u, m, 64); l23 = __hadd2(l23, c.h);
            c.u = (u32)__shfl_xor((int)((HC){.h = o01}).u, m, 64); o01 = __hadd2(o01, c.h);
            c.u = (u32)__shfl_xor((int)((HC){.h = o23}).u, m, 64); o23 = __hadd2(o23, c.h);
        }
        // exact pad correction: each pad contributed ex=1 and x = node0's state
        int npads = padded4 - cnt;
        if (npads) {
            float4 g0 = *(const float4*)(Gb + lpart * 4);   // node 0 slot
            union { float4 f; __half2 h[4]; } g0u; g0u.f = g0;
            __half2 np = __float2half2_rn((float)npads);
            l01 = __hsub2(l01, np);
            l23 = __hsub2(l23, np);
            __half2 nneg = __hneg2(np);
            o01 = __hfma2(nneg, g0u.h[2], o01);
            o23 = __hfma2(nneg, g0u.h[3], o23);
        }
    }
    if (eidx == 0) {
        float4 r;
        if (cnt > 0) {
            float l0 = __low2float(l01), l1 = __high2float(l01);
            float l2 = __low2float(l23), l3 = __high2float(l23);
            float o0 = __low2float(o01), o1 = __high2float(o01);
            float o2 = __low2float(o23), o3 = __high2float(o23);
            r.x = fmaxf(o0 * __builtin_amdgcn_rcpf(l0), 0.f);
            r.y = fmaxf(o1 * __builtin_amdgcn_rcpf(l1), 0.f);
            r.z = fmaxf(o2 * __builtin_amdgcn_rcpf(l2), 0.f);
            r.w = fmaxf(o3 * __builtin_amdgcn_rcpf(l3), 0.f);
        } else {
            r = make_float4(0.f, 0.f, 0.f, 0.f);
        }
        *(float4*)(out + (size_t)n * BD + b * 64 + lpart * 4) = r;
    }
}

extern "C" void kernel_launch(void* const* d_in, const int* in_sizes, int n_in,
                              void* d_out, int out_size, void* d_ws, size_t ws_size,
                              hipStream_t stream) {
    const float* state  = (const float*)d_in[0];
    // d_in[1] = feature (unused by the math)
    const float* weight = (const float*)d_in[2];
    const int*   src    = (const int*)d_in[3];
    const int*   dst    = (const int*)d_in[4];
    const float* dist   = (const float*)d_in[5];

    // workspace layout (16B-aligned head first): total ~33 MB
    u32*    G      = (u32*)d_ws;                            // 8*SLICE u32 = 20.48 MB
    __half* Pd     = (__half*)(G + (size_t)8 * SLICE);      // 8*SLICE half = 10.24 MB
    u32*    bucket = (u32*)(Pd + (size_t)8 * SLICE);        // N*CAPR u32 = 2.24 MB
    int*    counts = (int*)(bucket + (size_t)N_NODES * CAPR); // N ints (contiguous after bucket)

    // one memset zeroes bucket (pad records decode as {src=0, hd=0}) and counts
    hipMemsetAsync(bucket, 0, ((size_t)N_NODES * CAPR + N_NODES) * sizeof(u32), stream);
    prep_kernel<<<1875, 256, 0, stream>>>(src, dst, dist, counts, bucket,
                                          state, weight, G, Pd);
    gat_aggregate<<<N_NODES * 2, 256, 0, stream>>>(G, Pd, counts, bucket, (float*)d_out);
}

// Round 12
// 140.183 us; speedup vs baseline: 1.0884x; 1.0143x over previous
//
#include <hip/hip_runtime.h>
#include <hip/hip_fp16.h>
#include <math.h>

#define N_NODES 10000
#define N_EDGES 160000
#define B_ 8
#define D_ 64
#define BD 512          // B_*D_
#define ROWS 80000      // N_NODES*B_
#define SLICE 640000    // N_NODES*64 words per batch-slice
#define CAP 48          // max edges kept per node; P(Poisson(16) >= 48) ~ 6e-11
#define CAPR 56         // bucket row stride

typedef _Float16 f16x8 __attribute__((ext_vector_type(8)));
typedef float f32x4 __attribute__((ext_vector_type(4)));
typedef float f4v __attribute__((ext_vector_type(4)));
typedef unsigned int u32;

union HU { _Float16 f; unsigned short u; };
union HC { u32 u; __half2 h; };

// ---------------- fused prep: bucket-scatter (blocks 0..624) + MFMA proj (625..1874) ----
// scatter: bucket[d*CAPR + pos] = src | (half(dist*log2e) << 16). Pad slots stay 0
//          (memset) -> decode {src=0, hd=0} -> exp contribution exactly 1.
// proj: P[m][c] = sum_k state[m][k]*W[(c>=64?64:0)+k][c&63], slice-major planar-quad:
//   row m = node*8+b -> G words [b*SLICE + node*64 + q*4 .. +3] = {p01,p23,x01,x23}
//                        Pd[b*SLICE + node*64 + d] = half(p_dst)   (d-linear)
// LDS: Bt (18.4 KB) is DEAD after B-fragments are hoisted to registers; reused for
// Ps2/Ps staging -> 27.6 KB total -> 5 blocks/CU.
__global__ void __launch_bounds__(256, 4) prep_kernel(
    const int* __restrict__ src, const int* __restrict__ dst,
    const float* __restrict__ dist, int* __restrict__ counts, u32* __restrict__ bucket,
    const float* __restrict__ state, const float* __restrict__ weight,
    u32* __restrict__ G, __half* __restrict__ Pd) {
    __shared__ _Float16 At[64 * 72];          // 9 KB  (fp16 state tile, also x source)
    __shared__ char smemB[128 * 72 * 2];      // 18.4 KB: Bt, then Ps2+Ps
    _Float16* Bt = (_Float16*)smemB;                        // [128][72]
    unsigned short* Ps2 = (unsigned short*)smemB;           // [64][68] p_src
    unsigned short* Ps  = (unsigned short*)(smemB + 8704);  // [64][64] p_dst
    int bid = blockIdx.x;
    int tid = threadIdx.x;

    if (bid < 625) {
        // ---- scatter (625*256 == N_EDGES exactly) ----
        int e = bid * 256 + tid;
        int s = src[e];
        int d = dst[e];
        float di = dist[e];
        int pos = atomicAdd(&counts[d], 1);
        if (pos < CAP) {
            unsigned short hd = __half_as_ushort(__float2half_rn(di * 1.44269504f));
            bucket[d * CAPR + pos] = (u32)s | ((u32)hd << 16);
        }
        return;
    }

    // ---- proj ----
    int row0 = (bid - 625) * 64;
    int wave = tid >> 6, lane = tid & 63;
    int quad = lane >> 4, m16 = lane & 15;
    int m_loc = wave * 16 + m16;

    // stage state tile (read-once stream) -> fp16 LDS
    const f4v* st4 = (const f4v*)(state + (size_t)row0 * 64);
    for (int i = tid; i < 1024; i += 256) {
        int r = i >> 4, c4 = (i & 15) << 2;
        f4v v = __builtin_nontemporal_load(&st4[i]);
        union { short4 s; _Float16 h[4]; } u;
        u.h[0] = (_Float16)v[0]; u.h[1] = (_Float16)v[1];
        u.h[2] = (_Float16)v[2]; u.h[3] = (_Float16)v[3];
        *(short4*)&At[r * 72 + c4] = u.s;
    }
    // stage weight (32 KB, L2-resident across blocks) transposed -> Bt[n][k]
    const f4v* w4 = (const f4v*)weight;
    for (int i = tid; i < 2048; i += 256) {
        int r = i >> 4, c4 = (i & 15) << 2;    // r in [0,128): r = h*64+k
        f4v v = w4[i];
        int h = r >> 6, k = r & 63;
        int nb = h * 64 + c4;
        Bt[(nb + 0) * 72 + k] = (_Float16)v[0];
        Bt[(nb + 1) * 72 + k] = (_Float16)v[1];
        Bt[(nb + 2) * 72 + k] = (_Float16)v[2];
        Bt[(nb + 3) * 72 + k] = (_Float16)v[3];
    }
    __syncthreads();

    // hoist all B-fragments into registers; Bt LDS becomes dead after this
    f16x8 bf0[8], bf1[8];
#pragma unroll
    for (int tcol = 0; tcol < 8; tcol++) {
        int n = tcol * 16 + m16;
        bf0[tcol] = *(const f16x8*)&Bt[n * 72 + quad * 8];
        bf1[tcol] = *(const f16x8*)&Bt[n * 72 + 32 + quad * 8];
    }
    f16x8 a0 = *(const f16x8*)&At[m_loc * 72 + quad * 8];
    f16x8 a1 = *(const f16x8*)&At[m_loc * 72 + 32 + quad * 8];
    __syncthreads();   // everyone done with Bt; reuse as Ps2/Ps

#pragma unroll
    for (int tcol = 0; tcol < 8; tcol++) {
        int n = tcol * 16 + m16;
        f32x4 acc = {0.f, 0.f, 0.f, 0.f};
        acc = __builtin_amdgcn_mfma_f32_16x16x32_f16(a0, bf0[tcol], acc, 0, 0, 0);
        acc = __builtin_amdgcn_mfma_f32_16x16x32_f16(a1, bf1[tcol], acc, 0, 0, 0);
#pragma unroll
        for (int r = 0; r < 4; r++) {
            int ml = wave * 16 + quad * 4 + r;
            unsigned short ph = __half_as_ushort(__float2half_rn(acc[r]));
            if (tcol < 4) Ps2[ml * 68 + n] = ph;
            else          Ps[ml * 64 + (n - 64)] = ph;
        }
    }
    __syncthreads();

    // coalesced G write, planar-quad: one float4 per (row, quad) = {p01,p23,x01,x23}
    const u32* Ps2w = (const u32*)Ps2;
    const u32* Atw = (const u32*)At;
    for (int i = tid; i < 1024; i += 256) {
        int row = i >> 4, q = i & 15;
        int m = row0 + row;
        size_t base = (size_t)(m & 7) * SLICE + (size_t)(m >> 3) * 64;
        u32 p01 = Ps2w[row * 34 + q * 2];
        u32 p23 = Ps2w[row * 34 + q * 2 + 1];
        u32 x01 = Atw[row * 36 + q * 2];
        u32 x23 = Atw[row * 36 + q * 2 + 1];
        float4 v = make_float4(__uint_as_float(p01), __uint_as_float(p23),
                               __uint_as_float(x01), __uint_as_float(x23));
        *(float4*)&G[base + q * 4] = v;
    }
    // coalesced Pd write: 512 float4 (8 lanes = one row's 128 B)
    for (int i = tid; i < 512; i += 256) {
        int row = i >> 3, seg = i & 7;
        int m = row0 + row;
        size_t base = (size_t)(m & 7) * SLICE + (size_t)(m >> 3) * 64;
        *(float4*)&Pd[base + seg * 8] = *(const float4*)&Ps[row * 64 + seg * 8];
    }
}

// ---------------- fused segment-softmax + aggregate: 2 node-tasks per wave ------------
// planar-quad, maskless, pad-to-4 with 8-wide main loop + 4-wide tail (R11 loop body).
// Each wave handles nodes n0,n1 of slice b = blockIdx&7. Both tasks' counts/Pd/first
// records+gathers are prefetched up front (8 independent loads in flight), then the
// two task loops run sequentially -- task1's startup chain hides behind task0's work.
__global__ void __launch_bounds__(256) gat_aggregate(
    const u32* __restrict__ G,          // planar-quad slice-major [b][node][16 quads][4 words]
    const __half* __restrict__ Pds,     // slice-major [b][node][64], d-linear
    const int* __restrict__ counts,
    const u32* __restrict__ bucket,
    float* __restrict__ out) {
    int bid = blockIdx.x;
    int b = bid & 7;
    int grp = bid >> 3;                 // 0..1249
    int wave = threadIdx.x >> 6;
    int lane = threadIdx.x & 63;
    int n0 = (grp << 3) + (wave << 1);  // 8 nodes per block, 2 per wave
    int n1 = n0 + 1;
    int eidx = lane >> 4;    // edge group 0..3
    int lpart = lane & 15;   // element quad 0..15

    const u32* Gb = G + (size_t)b * SLICE;
    const __half* Pb = Pds + (size_t)b * SLICE;

    // ---- joint prologue: everything for both tasks issued up front ----
    int cnt0 = counts[n0]; if (cnt0 > CAP) cnt0 = CAP;
    int cnt1 = counts[n1]; if (cnt1 > CAP) cnt1 = CAP;
    const u32* ep0 = bucket + n0 * CAPR;
    const u32* ep1 = bucket + n1 * CAPR;

    union { double d; __half2 h[2]; } pdu0, pdu1;
    pdu0.d = *(const double*)(Pb + n0 * 64 + lpart * 4);
    pdu1.d = *(const double*)(Pb + n1 * 64 + lpart * 4);

    // unconditional prefetch (bucket rows zeroed; indices <= 7 < CAPR always valid)
    u32 rA0 = ep0[eidx], rB0 = ep0[4 + eidx];
    u32 rA1 = ep1[eidx], rB1 = ep1[4 + eidx];
    float4 gA0 = *(const float4*)(Gb + (size_t)(rA0 & 0xffffu) * 64 + lpart * 4);
    float4 gB0 = *(const float4*)(Gb + (size_t)(rB0 & 0xffffu) * 64 + lpart * 4);
    float4 gA1 = *(const float4*)(Gb + (size_t)(rA1 & 0xffffu) * 64 + lpart * 4);
    float4 gB1 = *(const float4*)(Gb + (size_t)(rB1 & 0xffffu) * 64 + lpart * 4);
    __half hh;
    hh = __ushort_as_half((unsigned short)(rA0 >> 16)); __half2 dA0 = __halves2half2(hh, hh);
    hh = __ushort_as_half((unsigned short)(rB0 >> 16)); __half2 dB0 = __halves2half2(hh, hh);
    hh = __ushort_as_half((unsigned short)(rA1 >> 16)); __half2 dA1 = __halves2half2(hh, hh);
    hh = __ushort_as_half((unsigned short)(rB1 >> 16)); __half2 dB1 = __halves2half2(hh, hh);

    const __half2 c06 = __float2half2_rn(0.6f);
    const __half2 c04 = __float2half2_rn(0.4f);

    auto edge_body = [&](float4 g, __half2 dd, __half2 pd01, __half2 pd23,
                         __half2& l01, __half2& l23, __half2& o01, __half2& o23) {
        union { float4 f; __half2 h[4]; } gu; gu.f = g;
        __half2 z01 = __hadd2(gu.h[0], pd01);
        __half2 z23 = __hadd2(gu.h[1], pd23);
        HC zz01, zz23, az01, az23;
        zz01.h = z01; zz23.h = z23;
        az01.u = zz01.u & 0x7fff7fffu;    // |z|
        az23.u = zz23.u & 0x7fff7fffu;
        __half2 lk01 = __hfma2(az01.h, c04, __hmul2(z01, c06));  // leaky_relu(0.2)
        __half2 lk23 = __hfma2(az23.h, c04, __hmul2(z23, c06));
        __half2 a01 = __hmul2(lk01, dd);
        __half2 a23 = __hmul2(lk23, dd);
        __half2 e01 = __halves2half2(hexp2(__low2half(a01)), hexp2(__high2half(a01)));
        __half2 e23 = __halves2half2(hexp2(__low2half(a23)), hexp2(__high2half(a23)));
        l01 = __hadd2(l01, e01);
        l23 = __hadd2(l23, e23);
        o01 = __hfma2(e01, gu.h[2], o01);
        o23 = __hfma2(e23, gu.h[3], o23);
    };

    auto run_task = [&](const u32* ep, int cnt, __half2 pd01, __half2 pd23,
                        float4 gA, float4 gB, __half2 dA, __half2 dB,
                        __half2& l01, __half2& l23, __half2& o01, __half2& o23) {
        int padded4 = (cnt + 3) & ~3;
        int full8 = padded4 & ~7;
        if (full8 > 0) {
            int j = 0;
            for (;;) {
                int jn = j + 8;
                bool more = jn < full8;   // wave-uniform
                float4 gA2, gB2; __half2 dA2, dB2;
                if (more) {
                    u32 rA2 = ep[jn + eidx];
                    u32 rB2 = ep[jn + 4 + eidx];
                    gA2 = *(const float4*)(Gb + (size_t)(rA2 & 0xffffu) * 64 + lpart * 4);
                    gB2 = *(const float4*)(Gb + (size_t)(rB2 & 0xffffu) * 64 + lpart * 4);
                    __half h2a = __ushort_as_half((unsigned short)(rA2 >> 16));
                    __half h2b = __ushort_as_half((unsigned short)(rB2 >> 16));
                    dA2 = __halves2half2(h2a, h2a);
                    dB2 = __halves2half2(h2b, h2b);
                }
                edge_body(gA, dA, pd01, pd23, l01, l23, o01, o23);
                edge_body(gB, dB, pd01, pd23, l01, l23, o01, o23);
                if (!more) break;
                j = jn; gA = gA2; gB = gB2; dA = dA2; dB = dB2;
            }
            if (padded4 > full8) {   // one 4-edge tail chain
                u32 rec = ep[full8 + eidx];
                float4 g = *(const float4*)(Gb + (size_t)(rec & 0xffffu) * 64 + lpart * 4);
                __half hd = __ushort_as_half((unsigned short)(rec >> 16));
                edge_body(g, __halves2half2(hd, hd), pd01, pd23, l01, l23, o01, o23);
            }
        } else if (padded4 > 0) {
            edge_body(gA, dA, pd01, pd23, l01, l23, o01, o23);   // tail == prefetched first 4
        }
    };

    __half2 zero = __float2half2_rn(0.f);
    __half2 l01a = zero, l23a = zero, o01a = zero, o23a = zero;
    __half2 l01b = zero, l23b = zero, o01b = zero, o23b = zero;

    run_task(ep0, cnt0, pdu0.h[0], pdu0.h[1], gA0, gB0, dA0, dB0, l01a, l23a, o01a, o23a);
    run_task(ep1, cnt1, pdu1.h[0], pdu1.h[1], gA1, gB1, dA1, dB1, l01b, l23b, o01b, o23b);

    // node-0 slot for pad correction (shared by both tasks)
    float4 g0 = *(const float4*)(Gb + lpart * 4);
    union { float4 f; __half2 h[4]; } g0u; g0u.f = g0;

    auto finish = [&](int cnt, __half2& l01, __half2& l23, __half2& o01, __half2& o23) {
        if (cnt <= 0) return;
#pragma unroll
        for (int m = 16; m <= 32; m <<= 1) {
            HC c;
            c.u = (u32)__shfl_xor((int)((HC){.h = l01}).u, m, 64); l01 = __hadd2(l01, c.h);
            c.u = (u32)__shfl_xor((int)((HC){.h = l23}).u, m, 64); l23 = __hadd2(l23, c.h);
            c.u = (u32)__shfl_xor((int)((HC){.h = o01}).u, m, 64); o01 = __hadd2(o01, c.h);
            c.u = (u32)__shfl_xor((int)((HC){.h = o23}).u, m, 64); o23 = __hadd2(o23, c.h);
        }
        int npads = ((cnt + 3) & ~3) - cnt;
        if (npads) {   // each pad contributed ex=1 and x = node0's state: subtract exactly
            __half2 np = __float2half2_rn((float)npads);
            l01 = __hsub2(l01, np);
            l23 = __hsub2(l23, np);
            __half2 nneg = __hneg2(np);
            o01 = __hfma2(nneg, g0u.h[2], o01);
            o23 = __hfma2(nneg, g0u.h[3], o23);
        }
    };
    finish(cnt0, l01a, l23a, o01a, o23a);
    finish(cnt1, l01b, l23b, o01b, o23b);

    if (eidx == 0) {
        auto emit = [&](int n, int cnt, __half2 l01, __half2 l23, __half2 o01, __half2 o23) {
            float4 r;
            if (cnt > 0) {
                float l0 = __low2float(l01), l1 = __high2float(l01);
                float l2 = __low2float(l23), l3 = __high2float(l23);
                float o0 = __low2float(o01), o1 = __high2float(o01);
                float o2 = __low2float(o23), o3 = __high2float(o23);
                r.x = fmaxf(o0 * __builtin_amdgcn_rcpf(l0), 0.f);
                r.y = fmaxf(o1 * __builtin_amdgcn_rcpf(l1), 0.f);
                r.z = fmaxf(o2 * __builtin_amdgcn_rcpf(l2), 0.f);
                r.w = fmaxf(o3 * __builtin_amdgcn_rcpf(l3), 0.f);
            } else {
                r = make_float4(0.f, 0.f, 0.f, 0.f);
            }
            *(float4*)(out + (size_t)n * BD + b * 64 + lpart * 4) = r;
        };
        emit(n0, cnt0, l01a, l23a, o01a, o23a);
        emit(n1, cnt1, l01b, l23b, o01b, o23b);
    }
}

extern "C" void kernel_launch(void* const* d_in, const int* in_sizes, int n_in,
                              void* d_out, int out_size, void* d_ws, size_t ws_size,
                              hipStream_t stream) {
    const float* state  = (const float*)d_in[0];
    // d_in[1] = feature (unused by the math)
    const float* weight = (const float*)d_in[2];
    const int*   src    = (const int*)d_in[3];
    const int*   dst    = (const int*)d_in[4];
    const float* dist   = (const float*)d_in[5];

    // workspace layout (16B-aligned head first): total ~33 MB
    u32*    G      = (u32*)d_ws;                            // 8*SLICE u32 = 20.48 MB
    __half* Pd     = (__half*)(G + (size_t)8 * SLICE);      // 8*SLICE half = 10.24 MB
    u32*    bucket = (u32*)(Pd + (size_t)8 * SLICE);        // N*CAPR u32 = 2.24 MB
    int*    counts = (int*)(bucket + (size_t)N_NODES * CAPR); // N ints (contiguous after bucket)

    // one memset zeroes bucket (pad records decode as {src=0, hd=0}) and counts
    hipMemsetAsync(bucket, 0, ((size_t)N_NODES * CAPR + N_NODES) * sizeof(u32), stream);
    prep_kernel<<<1875, 256, 0, stream>>>(src, dst, dist, counts, bucket,
                                          state, weight, G, Pd);
    gat_aggregate<<<N_NODES, 256, 0, stream>>>(G, Pd, counts, bucket, (float*)d_out);
}

// Round 13
// 136.693 us; speedup vs baseline: 1.1162x; 1.0255x over previous
//
#include <hip/hip_runtime.h>
#include <hip/hip_fp16.h>
#include <math.h>

#define N_NODES 10000
#define N_EDGES 160000
#define B_ 8
#define D_ 64
#define BD 512          // B_*D_
#define ROWS 80000      // N_NODES*B_
#define SLICE 640000    // N_NODES*64 words per batch-slice
#define CAP 48          // max edges kept per node; P(Poisson(16) >= 48) ~ 6e-11
#define CAPR 56         // bucket row stride

typedef _Float16 f16x8 __attribute__((ext_vector_type(8)));
typedef float f32x4 __attribute__((ext_vector_type(4)));
typedef float f4v __attribute__((ext_vector_type(4)));
typedef unsigned int u32;

union HU { _Float16 f; unsigned short u; };
union HC { u32 u; __half2 h; };

// ---------------- fused prep: per-block edge-scatter + MFMA proj (1250 blocks) --------
// Each block: (a) scatters 128 edges into buckets -- bucket[d*CAPR+pos] =
// src | (half(dist*log2e)<<16), counts via atomic; the ~600-cyc atomic/scatter chain
// overlaps the same block's staging + MFMA work. (b) projects 64 state rows:
// P[m][c] = sum_k state[m][k]*W[(c>=64?64:0)+k][c&63], written slice-major planar-quad:
//   row m = node*8+b -> G words [b*SLICE + node*64 + q*4 .. +3] = {p01,p23,x01,x23}
//                        Pd[b*SLICE + node*64 + d] = half(p_dst)   (d-linear)
// LDS: Bt (18.4 KB) dead after B-fragments hoisted to registers; reused for Ps2/Ps.
__global__ void __launch_bounds__(256, 4) prep_kernel(
    const int* __restrict__ src, const int* __restrict__ dst,
    const float* __restrict__ dist, int* __restrict__ counts, u32* __restrict__ bucket,
    const float* __restrict__ state, const float* __restrict__ weight,
    u32* __restrict__ G, __half* __restrict__ Pd) {
    __shared__ _Float16 At[64 * 72];          // 9 KB  (fp16 state tile, also x source)
    __shared__ char smemB[128 * 72 * 2];      // 18.4 KB: Bt, then Ps2+Ps
    _Float16* Bt = (_Float16*)smemB;                        // [128][72]
    unsigned short* Ps2 = (unsigned short*)smemB;           // [64][68] p_src
    unsigned short* Ps  = (unsigned short*)(smemB + 8704);  // [64][64] p_dst
    int bid = blockIdx.x;
    int tid = threadIdx.x;

    // ---- edge scatter: 128 edges per block (1250*128 == N_EDGES), issued first so
    //      its latency chain runs under the staging/MFMA work below ----
    int s_e, d_e; float di_e;
    bool do_edge = tid < 128;
    if (do_edge) {
        int e = bid * 128 + tid;
        s_e = src[e];
        d_e = dst[e];
        di_e = dist[e];
    }

    // ---- proj staging ----
    int row0 = bid * 64;
    int wave = tid >> 6, lane = tid & 63;
    int quad = lane >> 4, m16 = lane & 15;
    int m_loc = wave * 16 + m16;

    // stage state tile (read-once stream) -> fp16 LDS
    const f4v* st4 = (const f4v*)(state + (size_t)row0 * 64);
    for (int i = tid; i < 1024; i += 256) {
        int r = i >> 4, c4 = (i & 15) << 2;
        f4v v = __builtin_nontemporal_load(&st4[i]);
        union { short4 s; _Float16 h[4]; } u;
        u.h[0] = (_Float16)v[0]; u.h[1] = (_Float16)v[1];
        u.h[2] = (_Float16)v[2]; u.h[3] = (_Float16)v[3];
        *(short4*)&At[r * 72 + c4] = u.s;
    }
    // stage weight (32 KB, L2-resident across blocks) transposed -> Bt[n][k]
    const f4v* w4 = (const f4v*)weight;
    for (int i = tid; i < 2048; i += 256) {
        int r = i >> 4, c4 = (i & 15) << 2;    // r in [0,128): r = h*64+k
        f4v v = w4[i];
        int h = r >> 6, k = r & 63;
        int nb = h * 64 + c4;
        Bt[(nb + 0) * 72 + k] = (_Float16)v[0];
        Bt[(nb + 1) * 72 + k] = (_Float16)v[1];
        Bt[(nb + 2) * 72 + k] = (_Float16)v[2];
        Bt[(nb + 3) * 72 + k] = (_Float16)v[3];
    }

    // complete the edge scatter (atomic + scattered 4B store) while LDS fills drain
    if (do_edge) {
        int pos = atomicAdd(&counts[d_e], 1);
        if (pos < CAP) {
            unsigned short hd = __half_as_ushort(__float2half_rn(di_e * 1.44269504f));
            bucket[d_e * CAPR + pos] = (u32)s_e | ((u32)hd << 16);
        }
    }
    __syncthreads();

    // hoist all B-fragments into registers; Bt LDS becomes dead after this
    f16x8 bf0[8], bf1[8];
#pragma unroll
    for (int tcol = 0; tcol < 8; tcol++) {
        int n = tcol * 16 + m16;
        bf0[tcol] = *(const f16x8*)&Bt[n * 72 + quad * 8];
        bf1[tcol] = *(const f16x8*)&Bt[n * 72 + 32 + quad * 8];
    }
    f16x8 a0 = *(const f16x8*)&At[m_loc * 72 + quad * 8];
    f16x8 a1 = *(const f16x8*)&At[m_loc * 72 + 32 + quad * 8];
    __syncthreads();   // everyone done with Bt; reuse as Ps2/Ps

#pragma unroll
    for (int tcol = 0; tcol < 8; tcol++) {
        int n = tcol * 16 + m16;
        f32x4 acc = {0.f, 0.f, 0.f, 0.f};
        acc = __builtin_amdgcn_mfma_f32_16x16x32_f16(a0, bf0[tcol], acc, 0, 0, 0);
        acc = __builtin_amdgcn_mfma_f32_16x16x32_f16(a1, bf1[tcol], acc, 0, 0, 0);
#pragma unroll
        for (int r = 0; r < 4; r++) {
            int ml = wave * 16 + quad * 4 + r;
            unsigned short ph = __half_as_ushort(__float2half_rn(acc[r]));
            if (tcol < 4) Ps2[ml * 68 + n] = ph;
            else          Ps[ml * 64 + (n - 64)] = ph;
        }
    }
    __syncthreads();

    // coalesced G write, planar-quad: one float4 per (row, quad) = {p01,p23,x01,x23}
    const u32* Ps2w = (const u32*)Ps2;
    const u32* Atw = (const u32*)At;
    for (int i = tid; i < 1024; i += 256) {
        int row = i >> 4, q = i & 15;
        int m = row0 + row;
        size_t base = (size_t)(m & 7) * SLICE + (size_t)(m >> 3) * 64;
        u32 p01 = Ps2w[row * 34 + q * 2];
        u32 p23 = Ps2w[row * 34 + q * 2 + 1];
        u32 x01 = Atw[row * 36 + q * 2];
        u32 x23 = Atw[row * 36 + q * 2 + 1];
        float4 v = make_float4(__uint_as_float(p01), __uint_as_float(p23),
                               __uint_as_float(x01), __uint_as_float(x23));
        *(float4*)&G[base + q * 4] = v;
    }
    // coalesced Pd write: 512 float4 (8 lanes = one row's 128 B)
    for (int i = tid; i < 512; i += 256) {
        int row = i >> 3, seg = i & 7;
        int m = row0 + row;
        size_t base = (size_t)(m & 7) * SLICE + (size_t)(m >> 3) * 64;
        *(float4*)&Pd[base + seg * 8] = *(const float4*)&Ps[row * 64 + seg * 8];
    }
}

// ---------------- fused segment-softmax + aggregate: 2 node-tasks per wave ------------
// planar-quad, maskless, pad-to-4 with 8-wide main loop + 4-wide tail.
// Each wave handles nodes n0,n1 of slice b = blockIdx&7. Both tasks' counts/Pd/first
// records+gathers are prefetched up front, then the two task loops run sequentially.
__global__ void __launch_bounds__(256) gat_aggregate(
    const u32* __restrict__ G,          // planar-quad slice-major [b][node][16 quads][4 words]
    const __half* __restrict__ Pds,     // slice-major [b][node][64], d-linear
    const int* __restrict__ counts,
    const u32* __restrict__ bucket,
    float* __restrict__ out) {
    int bid = blockIdx.x;
    int b = bid & 7;
    int grp = bid >> 3;                 // 0..1249
    int wave = threadIdx.x >> 6;
    int lane = threadIdx.x & 63;
    int n0 = (grp << 3) + (wave << 1);  // 8 nodes per block, 2 per wave
    int n1 = n0 + 1;
    int eidx = lane >> 4;    // edge group 0..3
    int lpart = lane & 15;   // element quad 0..15

    const u32* Gb = G + (size_t)b * SLICE;
    const __half* Pb = Pds + (size_t)b * SLICE;

    // ---- joint prologue: everything for both tasks issued up front ----
    int cnt0 = counts[n0]; if (cnt0 > CAP) cnt0 = CAP;
    int cnt1 = counts[n1]; if (cnt1 > CAP) cnt1 = CAP;
    const u32* ep0 = bucket + n0 * CAPR;
    const u32* ep1 = bucket + n1 * CAPR;

    union { double d; __half2 h[2]; } pdu0, pdu1;
    pdu0.d = *(const double*)(Pb + n0 * 64 + lpart * 4);
    pdu1.d = *(const double*)(Pb + n1 * 64 + lpart * 4);

    // unconditional prefetch (bucket rows zeroed; indices <= 7 < CAPR always valid)
    u32 rA0 = ep0[eidx], rB0 = ep0[4 + eidx];
    u32 rA1 = ep1[eidx], rB1 = ep1[4 + eidx];
    float4 gA0 = *(const float4*)(Gb + (size_t)(rA0 & 0xffffu) * 64 + lpart * 4);
    float4 gB0 = *(const float4*)(Gb + (size_t)(rB0 & 0xffffu) * 64 + lpart * 4);
    float4 gA1 = *(const float4*)(Gb + (size_t)(rA1 & 0xffffu) * 64 + lpart * 4);
    float4 gB1 = *(const float4*)(Gb + (size_t)(rB1 & 0xffffu) * 64 + lpart * 4);
    __half hh;
    hh = __ushort_as_half((unsigned short)(rA0 >> 16)); __half2 dA0 = __halves2half2(hh, hh);
    hh = __ushort_as_half((unsigned short)(rB0 >> 16)); __half2 dB0 = __halves2half2(hh, hh);
    hh = __ushort_as_half((unsigned short)(rA1 >> 16)); __half2 dA1 = __halves2half2(hh, hh);
    hh = __ushort_as_half((unsigned short)(rB1 >> 16)); __half2 dB1 = __halves2half2(hh, hh);

    const __half2 c06 = __float2half2_rn(0.6f);
    const __half2 c04 = __float2half2_rn(0.4f);

    auto edge_body = [&](float4 g, __half2 dd, __half2 pd01, __half2 pd23,
                         __half2& l01, __half2& l23, __half2& o01, __half2& o23) {
        union { float4 f; __half2 h[4]; } gu; gu.f = g;
        __half2 z01 = __hadd2(gu.h[0], pd01);
        __half2 z23 = __hadd2(gu.h[1], pd23);
        HC zz01, zz23, az01, az23;
        zz01.h = z01; zz23.h = z23;
        az01.u = zz01.u & 0x7fff7fffu;    // |z|
        az23.u = zz23.u & 0x7fff7fffu;
        __half2 lk01 = __hfma2(az01.h, c04, __hmul2(z01, c06));  // leaky_relu(0.2)
        __half2 lk23 = __hfma2(az23.h, c04, __hmul2(z23, c06));
        __half2 a01 = __hmul2(lk01, dd);
        __half2 a23 = __hmul2(lk23, dd);
        __half2 e01 = __halves2half2(hexp2(__low2half(a01)), hexp2(__high2half(a01)));
        __half2 e23 = __halves2half2(hexp2(__low2half(a23)), hexp2(__high2half(a23)));
        l01 = __hadd2(l01, e01);
        l23 = __hadd2(l23, e23);
        o01 = __hfma2(e01, gu.h[2], o01);
        o23 = __hfma2(e23, gu.h[3], o23);
    };

    auto run_task = [&](const u32* ep, int cnt, __half2 pd01, __half2 pd23,
                        float4 gA, float4 gB, __half2 dA, __half2 dB,
                        __half2& l01, __half2& l23, __half2& o01, __half2& o23) {
        int padded4 = (cnt + 3) & ~3;
        int full8 = padded4 & ~7;
        if (full8 > 0) {
            int j = 0;
            for (;;) {
                int jn = j + 8;
                bool more = jn < full8;   // wave-uniform
                float4 gA2, gB2; __half2 dA2, dB2;
                if (more) {
                    u32 rA2 = ep[jn + eidx];
                    u32 rB2 = ep[jn + 4 + eidx];
                    gA2 = *(const float4*)(Gb + (size_t)(rA2 & 0xffffu) * 64 + lpart * 4);
                    gB2 = *(const float4*)(Gb + (size_t)(rB2 & 0xffffu) * 64 + lpart * 4);
                    __half h2a = __ushort_as_half((unsigned short)(rA2 >> 16));
                    __half h2b = __ushort_as_half((unsigned short)(rB2 >> 16));
                    dA2 = __halves2half2(h2a, h2a);
                    dB2 = __halves2half2(h2b, h2b);
                }
                edge_body(gA, dA, pd01, pd23, l01, l23, o01, o23);
                edge_body(gB, dB, pd01, pd23, l01, l23, o01, o23);
                if (!more) break;
                j = jn; gA = gA2; gB = gB2; dA = dA2; dB = dB2;
            }
            if (padded4 > full8) {   // one 4-edge tail chain
                u32 rec = ep[full8 + eidx];
                float4 g = *(const float4*)(Gb + (size_t)(rec & 0xffffu) * 64 + lpart * 4);
                __half hd = __ushort_as_half((unsigned short)(rec >> 16));
                edge_body(g, __halves2half2(hd, hd), pd01, pd23, l01, l23, o01, o23);
            }
        } else if (padded4 > 0) {
            edge_body(gA, dA, pd01, pd23, l01, l23, o01, o23);   // tail == prefetched first 4
        }
    };

    __half2 zero = __float2half2_rn(0.f);
    __half2 l01a = zero, l23a = zero, o01a = zero, o23a = zero;
    __half2 l01b = zero, l23b = zero, o01b = zero, o23b = zero;

    run_task(ep0, cnt0, pdu0.h[0], pdu0.h[1], gA0, gB0, dA0, dB0, l01a, l23a, o01a, o23a);
    run_task(ep1, cnt1, pdu1.h[0], pdu1.h[1], gA1, gB1, dA1, dB1, l01b, l23b, o01b, o23b);

    // node-0 slot for pad correction (shared by both tasks)
    float4 g0 = *(const float4*)(Gb + lpart * 4);
    union { float4 f; __half2 h[4]; } g0u; g0u.f = g0;

    auto finish = [&](int cnt, __half2& l01, __half2& l23, __half2& o01, __half2& o23) {
        if (cnt <= 0) return;
#pragma unroll
        for (int m = 16; m <= 32; m <<= 1) {
            HC c;
            c.u = (u32)__shfl_xor((int)((HC){.h = l01}).u, m, 64); l01 = __hadd2(l01, c.h);
            c.u = (u32)__shfl_xor((int)((HC){.h = l23}).u, m, 64); l23 = __hadd2(l23, c.h);
            c.u = (u32)__shfl_xor((int)((HC){.h = o01}).u, m, 64); o01 = __hadd2(o01, c.h);
            c.u = (u32)__shfl_xor((int)((HC){.h = o23}).u, m, 64); o23 = __hadd2(o23, c.h);
        }
        int npads = ((cnt + 3) & ~3) - cnt;
        if (npads) {   // each pad contributed ex=1 and x = node0's state: subtract exactly
            __half2 np = __float2half2_rn((float)npads);
            l01 = __hsub2(l01, np);
            l23 = __hsub2(l23, np);
            __half2 nneg = __hneg2(np);
            o01 = __hfma2(nneg, g0u.h[2], o01);
            o23 = __hfma2(nneg, g0u.h[3], o23);
        }
    };
    finish(cnt0, l01a, l23a, o01a, o23a);
    finish(cnt1, l01b, l23b, o01b, o23b);

    if (eidx == 0) {
        auto emit = [&](int n, int cnt, __half2 l01, __half2 l23, __half2 o01, __half2 o23) {
            float4 r;
            if (cnt > 0) {
                float l0 = __low2float(l01), l1 = __high2float(l01);
                float l2 = __low2float(l23), l3 = __high2float(l23);
                float o0 = __low2float(o01), o1 = __high2float(o01);
                float o2 = __low2float(o23), o3 = __high2float(o23);
                r.x = fmaxf(o0 * __builtin_amdgcn_rcpf(l0), 0.f);
                r.y = fmaxf(o1 * __builtin_amdgcn_rcpf(l1), 0.f);
                r.z = fmaxf(o2 * __builtin_amdgcn_rcpf(l2), 0.f);
                r.w = fmaxf(o3 * __builtin_amdgcn_rcpf(l3), 0.f);
            } else {
                r = make_float4(0.f, 0.f, 0.f, 0.f);
            }
            *(float4*)(out + (size_t)n * BD + b * 64 + lpart * 4) = r;
        };
        emit(n0, cnt0, l01a, l23a, o01a, o23a);
        emit(n1, cnt1, l01b, l23b, o01b, o23b);
    }
}

extern "C" void kernel_launch(void* const* d_in, const int* in_sizes, int n_in,
                              void* d_out, int out_size, void* d_ws, size_t ws_size,
                              hipStream_t stream) {
    const float* state  = (const float*)d_in[0];
    // d_in[1] = feature (unused by the math)
    const float* weight = (const float*)d_in[2];
    const int*   src    = (const int*)d_in[3];
    const int*   dst    = (const int*)d_in[4];
    const float* dist   = (const float*)d_in[5];

    // workspace layout (16B-aligned head first): total ~33 MB
    u32*    G      = (u32*)d_ws;                            // 8*SLICE u32 = 20.48 MB
    __half* Pd     = (__half*)(G + (size_t)8 * SLICE);      // 8*SLICE half = 10.24 MB
    u32*    bucket = (u32*)(Pd + (size_t)8 * SLICE);        // N*CAPR u32 = 2.24 MB
    int*    counts = (int*)(bucket + (size_t)N_NODES * CAPR); // N ints (contiguous after bucket)

    // one memset zeroes bucket (pad records decode as {src=0, hd=0}) and counts
    hipMemsetAsync(bucket, 0, ((size_t)N_NODES * CAPR + N_NODES) * sizeof(u32), stream);
    prep_kernel<<<1250, 256, 0, stream>>>(src, dst, dist, counts, bucket,
                                          state, weight, G, Pd);
    gat_aggregate<<<N_NODES, 256, 0, stream>>>(G, Pd, counts, bucket, (float*)d_out);
}